// Round 8
// baseline (378.697 us; speedup 1.0000x reference)
//
#include <hip/hip_runtime.h>
#include <math.h>

#define CI 12
#define NHID 15
#define NBLK 6144                 // 8*3*16*16 image blocks of 32x32
#define NPIX (NBLK * 1024)

typedef int i32x4 __attribute__((ext_vector_type(4)));
typedef _Float16 h2 __attribute__((ext_vector_type(2)));

// pack two f32 -> f16x2 (RTZ, 1 inst)
static __device__ __forceinline__ int pkrtz(float lo, float hi) {
    return __builtin_bit_cast(int, __builtin_amdgcn_cvt_pkrtz(lo, hi));
}

// ---- hand-scheduled hot loop (f16 activations) -----------------------------
// Fixed VGPRs: C=v[32:35](0), BA=v[36:39], BB=v[40:43], BC=v[44:47],
// BD=v[48:51], DA=v[52:55], DB=v[56:59], DC=v[60:63], DD=v[64:67],
// tmp v68/v69, v70 = 0x211F211F (f16 0.01 x2). Weights: 16 AGPR quads.
// leaky in f16: B = pk_max(h, 0.01*h). Hazards: every MFMA->VALU-read gap
// >=34 cyc; every VALU->MFMA-src gap >=2 slots (R7-validated margins).
#define ACT(d0, d1, b) \
  "v_cvt_pkrtz_f16_f32 v68, " d0 ", " d1 "\n" \
  "v_pk_mul_f16 v69, v70, v68\n" \
  "v_pk_max_f16 " b ", v68, v69\n"

#define MFA(w) "v_mfma_f32_16x16x32_f16 v[52:55], %[" w "], v[36:39], v[32:35]\n"
#define MFB(w) "v_mfma_f32_16x16x32_f16 v[56:59], %[" w "], v[40:43], v[32:35]\n"
#define MFC(w) "v_mfma_f32_16x16x32_f16 v[60:63], %[" w "], v[44:47], v[32:35]\n"
#define MFD(w) "v_mfma_f32_16x16x32_f16 v[64:67], %[" w "], v[48:51], v[32:35]\n"

#define LAYER(w) \
  ACT("v52","v53","v36") ACT("v54","v55","v37") \
  ACT("v56","v57","v40") ACT("v58","v59","v41") \
  MFA(w) \
  ACT("v60","v61","v44") ACT("v62","v63","v45") \
  MFB(w) \
  ACT("v64","v65","v48") ACT("v66","v67","v49") \
  MFC(w) \
  "s_nop 1\n" \
  MFD(w)

__global__ __launch_bounds__(256, 3) void codec_main(
    const float* __restrict__ x,
    const float* __restrict__ Wh,   // [15][12][12]
    const float* __restrict__ bh,   // [15][12]
    const float* __restrict__ Wo,   // [12]
    const float* __restrict__ bo,   // [1]
    float* __restrict__ out,        // [1 + NPIX]
    float* __restrict__ loss_acc,   // ws[0], pre-zeroed
    unsigned* __restrict__ done_cnt)// ws[1], pre-zeroed
{
    __shared__ float tile[36 * 37]; // 32x32 + 2-halo, +1 col pad
    __shared__ float stage[4][256]; // per-wave delta staging
    __shared__ float wsum[4];

    const int n    = blockIdx.x;
    const int tid  = threadIdx.x;   // 0..255
    const int lane = tid & 63;
    const int wv   = tid >> 6;      // wave 0..3
    const int t    = lane & 15;
    const int q    = lane >> 4;

    // ---- stage image block into LDS (zero halo) ----
    {
        const int col = tid & 31;
        const int r0  = tid >> 5;
        #pragma unroll
        for (int i = 0; i < 6; ++i) {
            int idx = tid + i * 256;
            if (idx < 36 * 37) tile[idx] = 0.0f;
        }
        __syncthreads();
        const int bc  = n >> 8;
        const int blk = n & 255;
        const int by  = blk >> 4;
        const int bx  = blk & 15;
        #pragma unroll
        for (int p = 0; p < 4; ++p) {
            const int row = r0 + 8 * p;
            tile[(row + 2) * 37 + col + 2] =
                x[((size_t)bc * 512 + (size_t)(by * 32 + row)) * 512
                  + (size_t)(bx * 32 + col)];
        }
        __syncthreads();
    }

    // ---- weight A-frags (sparse-K, validated R4-R7), f16 ----
    // lane 16q+t: k=8q+j: j=0..3 <- W[t][4q+j]; (q==0,j==4) <- bias; else 0
    i32x4 wq[16];
    const bool wok = (t < CI) && (q < 3);
    #pragma unroll
    for (int l = 0; l < NHID; ++l) {
        float4 w = {0.f, 0.f, 0.f, 0.f};
        float  b = 0.f;
        if (wok) w = *(const float4*)(Wh + l * (CI * CI) + t * CI + 4 * q);
        if (wok && q == 0) b = bh[l * CI + t];
        wq[l] = (i32x4){ pkrtz(w.x, w.y), pkrtz(w.z, w.w), pkrtz(b, 0.f), 0 };
    }
    {
        float4 w = {0.f, 0.f, 0.f, 0.f};
        float  b = 0.f;
        if (t == 0 && q < 3) w = *(const float4*)(Wo + 4 * q);
        if (t == 0 && q == 0) b = bo[0];
        wq[15] = (i32x4){ pkrtz(w.x, w.y), pkrtz(w.z, w.w), pkrtz(b, 0.f), 0 };
    }

    // ---- per-lane feature offsets (elements): channel c=4q+r at (dy,dx) ----
    const int sh8  = q * 8;
    const int off0 = (int)(signed char)((0x00DCB8B4u >> sh8) & 0xFFu);
    const int off1 = (int)(signed char)((0x00DDD9B5u >> sh8) & 0xFFu);
    const int off2 = (int)(signed char)((0x00FEDAB6u >> sh8) & 0xFFu);
    const int off3 = (int)(signed char)((0x00FFDBB7u >> sh8) & 0xFFu);

    const int biasreg = (q == 0) ? 0x00003C00 : 0;   // k=4 slot = f16(1.0)
    int e = (wv * 8 + 2) * 37 + (t + 2);             // row 8wv, half 0

    float d2 = 0.0f;
    #pragma unroll 1
    for (int yi = 0; yi < 4; ++yi) {
        // chains: A=(row r,half0) B=(r,half1) C=(r+1,half0) D=(r+1,half1)
        const int fa0 = pkrtz(tile[e + off0],      tile[e + off1]);
        const int fa1 = pkrtz(tile[e + off2],      tile[e + off3]);
        const int fb0 = pkrtz(tile[e + off0 + 16], tile[e + off1 + 16]);
        const int fb1 = pkrtz(tile[e + off2 + 16], tile[e + off3 + 16]);
        const int fc0 = pkrtz(tile[e + off0 + 37], tile[e + off1 + 37]);
        const int fc1 = pkrtz(tile[e + off2 + 37], tile[e + off3 + 37]);
        const int fd0 = pkrtz(tile[e + off0 + 53], tile[e + off1 + 53]);
        const int fd1 = pkrtz(tile[e + off2 + 53], tile[e + off3 + 53]);
        const float vA = tile[e], vB = tile[e + 16];
        const float vC = tile[e + 37], vD = tile[e + 53];

        float pA, pB, pC, pD;
        asm volatile(
            "v_mov_b32 v70, 0x211f211f\n"
            "v_mov_b32 v32, 0\n" "v_mov_b32 v33, 0\n"
            "v_mov_b32 v34, 0\n" "v_mov_b32 v35, 0\n"
            "v_mov_b32 v38, %[bias]\n" "v_mov_b32 v39, 0\n"
            "v_mov_b32 v42, %[bias]\n" "v_mov_b32 v43, 0\n"
            "v_mov_b32 v46, %[bias]\n" "v_mov_b32 v47, 0\n"
            "v_mov_b32 v50, %[bias]\n" "v_mov_b32 v51, 0\n"
            "v_mov_b32 v36, %[fa0]\n" "v_mov_b32 v37, %[fa1]\n"
            "v_mov_b32 v40, %[fb0]\n" "v_mov_b32 v41, %[fb1]\n"
            "v_mov_b32 v44, %[fc0]\n" "v_mov_b32 v45, %[fc1]\n"
            "v_mov_b32 v48, %[fd0]\n" "v_mov_b32 v49, %[fd1]\n"
            MFA("w0") MFB("w0") MFC("w0") MFD("w0")
            LAYER("w1")  LAYER("w2")  LAYER("w3")  LAYER("w4")
            LAYER("w5")  LAYER("w6")  LAYER("w7")  LAYER("w8")
            LAYER("w9")  LAYER("w10") LAYER("w11") LAYER("w12")
            LAYER("w13") LAYER("w14") LAYER("w15")
            "s_nop 7\n" "s_nop 7\n" "s_nop 7\n"
            "v_mov_b32 %[pA], v52\n"
            "v_mov_b32 %[pB], v56\n"
            "v_mov_b32 %[pC], v60\n"
            "v_mov_b32 %[pD], v64\n"
            : [pA] "=v"(pA), [pB] "=v"(pB), [pC] "=v"(pC), [pD] "=v"(pD)
            : [w0] "a"(wq[0]),  [w1] "a"(wq[1]),  [w2] "a"(wq[2]),
              [w3] "a"(wq[3]),  [w4] "a"(wq[4]),  [w5] "a"(wq[5]),
              [w6] "a"(wq[6]),  [w7] "a"(wq[7]),  [w8] "a"(wq[8]),
              [w9] "a"(wq[9]),  [w10] "a"(wq[10]), [w11] "a"(wq[11]),
              [w12] "a"(wq[12]), [w13] "a"(wq[13]), [w14] "a"(wq[14]),
              [w15] "a"(wq[15]),
              [fa0] "v"(fa0), [fa1] "v"(fa1), [fb0] "v"(fb0), [fb1] "v"(fb1),
              [fc0] "v"(fc0), [fc1] "v"(fc1), [fd0] "v"(fd0), [fd1] "v"(fd1),
              [bias] "v"(biasreg)
            : "v32","v33","v34","v35","v36","v37","v38","v39",
              "v40","v41","v42","v43","v44","v45","v46","v47",
              "v48","v49","v50","v51","v52","v53","v54","v55",
              "v56","v57","v58","v59","v60","v61","v62","v63",
              "v64","v65","v66","v67","v68","v69","v70");

        if (lane < 16) {                   // D row 0 = prediction, lanes 0..15
            const float qA = fminf(fmaxf(pA, -1.0f), 1.0f);
            const float uA = vA - qA + 1.0f;
            const float dA = uA - ((uA < 2.0f) ? 1.0f : 3.0f); // fmod(u,2)-1
            const float qB = fminf(fmaxf(pB, -1.0f), 1.0f);
            const float uB = vB - qB + 1.0f;
            const float dB = uB - ((uB < 2.0f) ? 1.0f : 3.0f);
            const float qC = fminf(fmaxf(pC, -1.0f), 1.0f);
            const float uC = vC - qC + 1.0f;
            const float dC = uC - ((uC < 2.0f) ? 1.0f : 3.0f);
            const float qD = fminf(fmaxf(pD, -1.0f), 1.0f);
            const float uD = vD - qD + 1.0f;
            const float dD = uD - ((uD < 2.0f) ? 1.0f : 3.0f);
            const int r = 2 * yi;
            stage[wv][r * 32 + t]            = dA;
            stage[wv][r * 32 + 16 + t]       = dB;
            stage[wv][(r + 1) * 32 + t]      = dC;
            stage[wv][(r + 1) * 32 + 16 + t] = dD;
            d2 = fmaf(dA, dA, fmaf(dB, dB, fmaf(dC, dC, fmaf(dD, dD, d2))));
        }
        e += 74;                            // two rows
    }

    // ---- coalesced delta store: wave's 256 floats = rows [8wv, 8wv+8) ----
    float* outp = out + 1 + (size_t)n * 1024 + wv * 256;
    #pragma unroll
    for (int j = 0; j < 4; ++j)
        outp[j * 64 + lane] = stage[wv][j * 64 + lane];

    // ---- loss reduction + fused last-block finalize ----
    #pragma unroll
    for (int off = 8; off > 0; off >>= 1) d2 += __shfl_down(d2, off, 64);
    if (lane == 0) wsum[wv] = d2;
    __syncthreads();
    if (tid == 0) {
        const float s = wsum[0] + wsum[1] + wsum[2] + wsum[3];
        __hip_atomic_fetch_add(loss_acc, s, __ATOMIC_RELEASE,
                               __HIP_MEMORY_SCOPE_AGENT);
        const unsigned old = __hip_atomic_fetch_add(done_cnt, 1u,
                               __ATOMIC_ACQ_REL, __HIP_MEMORY_SCOPE_AGENT);
        if (old == NBLK - 1) {
            const float tot = __hip_atomic_load(loss_acc, __ATOMIC_ACQUIRE,
                                                __HIP_MEMORY_SCOPE_AGENT);
            out[0] = 255.0f * sqrtf(tot / (float)NPIX);
        }
    }
}

extern "C" void kernel_launch(void* const* d_in, const int* in_sizes, int n_in,
                              void* d_out, int out_size, void* d_ws, size_t ws_size,
                              hipStream_t stream)
{
    const float* x  = (const float*)d_in[0];
    const float* Wh = (const float*)d_in[1];
    const float* bh = (const float*)d_in[2];
    const float* Wo = (const float*)d_in[3];
    const float* bo = (const float*)d_in[4];
    float* out = (float*)d_out;
    float*    acc = (float*)d_ws;
    unsigned* cnt = (unsigned*)d_ws + 1;

    hipMemsetAsync(d_ws, 0, 8, stream);   // graph-capture safe
    codec_main<<<NBLK, 256, 0, stream>>>(x, Wh, bh, Wo, bo, out, acc, cnt);
}

// Round 9
// 253.136 us; speedup vs baseline: 1.4960x; 1.4960x over previous
//
#include <hip/hip_runtime.h>
#include <math.h>

#define CI 12
#define NHID 15
#define NBLK 6144                 // 8*3*16*16 image blocks of 32x32
#define NPIX (NBLK * 1024)

typedef int i32x4 __attribute__((ext_vector_type(4)));

// pack two f32 -> f16x2 (RTZ, 1 inst)
static __device__ __forceinline__ int pkrtz(float lo, float hi) {
    return __builtin_bit_cast(int, __builtin_amdgcn_cvt_pkrtz(lo, hi));
}

// ---- hand-scheduled hot loop (f16 activations, ILP-paired) -----------------
// Fixed VGPRs: C=v[32:35](0), BA=v[36:39], BB=v[40:43], BC=v[44:47],
// BD=v[48:51], DA=v[52:55], DB=v[56:59], DC=v[60:63], DD=v[64:67],
// tmps v68-71, v72 = 0x211F211F (f16 0.01 x2). Weights: 16 AGPR quads.
// ACT2: two independent 3-chains interleaved -> dep distance 2 inst (no stall).
// Hazards (R7/R8-validated): MFMA D->VALU read gap >= 12 VALU + 3 MFMA;
// VALU write -> MFMA B-src gap >= 2 slots.
#define ACT2(d0, d1, d2, d3, b0, b1) \
  "v_cvt_pkrtz_f16_f32 v68, " d0 ", " d1 "\n" \
  "v_cvt_pkrtz_f16_f32 v69, " d2 ", " d3 "\n" \
  "v_pk_mul_f16 v70, v72, v68\n" \
  "v_pk_mul_f16 v71, v72, v69\n" \
  "v_pk_max_f16 " b0 ", v68, v70\n" \
  "v_pk_max_f16 " b1 ", v69, v71\n"

#define MFA(w) "v_mfma_f32_16x16x32_f16 v[52:55], %[" w "], v[36:39], v[32:35]\n"
#define MFB(w) "v_mfma_f32_16x16x32_f16 v[56:59], %[" w "], v[40:43], v[32:35]\n"
#define MFC(w) "v_mfma_f32_16x16x32_f16 v[60:63], %[" w "], v[44:47], v[32:35]\n"
#define MFD(w) "v_mfma_f32_16x16x32_f16 v[64:67], %[" w "], v[48:51], v[32:35]\n"

#define LAYER(w) \
  ACT2("v52","v53","v54","v55","v36","v37") \
  ACT2("v56","v57","v58","v59","v40","v41") \
  MFA(w) \
  ACT2("v60","v61","v62","v63","v44","v45") \
  MFB(w) \
  ACT2("v64","v65","v66","v67","v48","v49") \
  MFC(w) \
  "s_nop 1\n" \
  MFD(w)

__global__ __launch_bounds__(256, 3) void codec_main(
    const float* __restrict__ x,
    const float* __restrict__ Wh,   // [15][12][12]
    const float* __restrict__ bh,   // [15][12]
    const float* __restrict__ Wo,   // [12]
    const float* __restrict__ bo,   // [1]
    float* __restrict__ out,        // [1 + NPIX]
    float* __restrict__ loss_acc,   // ws[0], zeroed via memsetAsync
    unsigned* __restrict__ done_cnt)// ws[1], zeroed via memsetAsync
{
    __shared__ float tile[36 * 37]; // 32x32 + 2-halo, +1 col pad
    __shared__ float stage[4][256]; // per-wave delta staging
    __shared__ float wsum[4];

    const int n    = blockIdx.x;
    const int tid  = threadIdx.x;   // 0..255
    const int lane = tid & 63;
    const int wv   = tid >> 6;      // wave 0..3
    const int t    = lane & 15;
    const int q    = lane >> 4;

    // ---- stage image block into LDS (zero halo) ----
    {
        const int col = tid & 31;
        const int r0  = tid >> 5;
        #pragma unroll
        for (int i = 0; i < 6; ++i) {
            int idx = tid + i * 256;
            if (idx < 36 * 37) tile[idx] = 0.0f;
        }
        __syncthreads();
        const int bc  = n >> 8;
        const int blk = n & 255;
        const int by  = blk >> 4;
        const int bx  = blk & 15;
        #pragma unroll
        for (int p = 0; p < 4; ++p) {
            const int row = r0 + 8 * p;
            tile[(row + 2) * 37 + col + 2] =
                x[((size_t)bc * 512 + (size_t)(by * 32 + row)) * 512
                  + (size_t)(bx * 32 + col)];
        }
        __syncthreads();
    }

    // ---- weight A-frags (sparse-K, validated R4-R8), f16 ----
    // lane 16q+t: k=8q+j: j=0..3 <- W[t][4q+j]; (q==0,j==4) <- bias; else 0
    i32x4 wq[16];
    const bool wok = (t < CI) && (q < 3);
    #pragma unroll
    for (int l = 0; l < NHID; ++l) {
        float4 w = {0.f, 0.f, 0.f, 0.f};
        float  b = 0.f;
        if (wok) w = *(const float4*)(Wh + l * (CI * CI) + t * CI + 4 * q);
        if (wok && q == 0) b = bh[l * CI + t];
        wq[l] = (i32x4){ pkrtz(w.x, w.y), pkrtz(w.z, w.w), pkrtz(b, 0.f), 0 };
    }
    {
        float4 w = {0.f, 0.f, 0.f, 0.f};
        float  b = 0.f;
        if (t == 0 && q < 3) w = *(const float4*)(Wo + 4 * q);
        if (t == 0 && q == 0) b = bo[0];
        wq[15] = (i32x4){ pkrtz(w.x, w.y), pkrtz(w.z, w.w), pkrtz(b, 0.f), 0 };
    }

    // ---- per-lane feature offsets (elements): channel c=4q+r at (dy,dx) ----
    const int sh8  = q * 8;
    const int off0 = (int)(signed char)((0x00DCB8B4u >> sh8) & 0xFFu);
    const int off1 = (int)(signed char)((0x00DDD9B5u >> sh8) & 0xFFu);
    const int off2 = (int)(signed char)((0x00FEDAB6u >> sh8) & 0xFFu);
    const int off3 = (int)(signed char)((0x00FFDBB7u >> sh8) & 0xFFu);

    const int biasreg = (q == 0) ? 0x00003C00 : 0;   // k=4 slot = f16(1.0)
    int e = (wv * 8 + 2) * 37 + (t + 2);             // row 8wv, half 0

    float d2 = 0.0f;
    #pragma unroll 1
    for (int yi = 0; yi < 4; ++yi) {
        // chains: A=(row r,half0) B=(r,half1) C=(r+1,half0) D=(r+1,half1)
        const int fa0 = pkrtz(tile[e + off0],      tile[e + off1]);
        const int fa1 = pkrtz(tile[e + off2],      tile[e + off3]);
        const int fb0 = pkrtz(tile[e + off0 + 16], tile[e + off1 + 16]);
        const int fb1 = pkrtz(tile[e + off2 + 16], tile[e + off3 + 16]);
        const int fc0 = pkrtz(tile[e + off0 + 37], tile[e + off1 + 37]);
        const int fc1 = pkrtz(tile[e + off2 + 37], tile[e + off3 + 37]);
        const int fd0 = pkrtz(tile[e + off0 + 53], tile[e + off1 + 53]);
        const int fd1 = pkrtz(tile[e + off2 + 53], tile[e + off3 + 53]);
        const float vA = tile[e], vB = tile[e + 16];
        const float vC = tile[e + 37], vD = tile[e + 53];

        float pA, pB, pC, pD;
        asm volatile(
            "v_mov_b32 v72, 0x211f211f\n"
            "v_mov_b32 v32, 0\n" "v_mov_b32 v33, 0\n"
            "v_mov_b32 v34, 0\n" "v_mov_b32 v35, 0\n"
            "v_mov_b32 v38, %[bias]\n" "v_mov_b32 v39, 0\n"
            "v_mov_b32 v42, %[bias]\n" "v_mov_b32 v43, 0\n"
            "v_mov_b32 v46, %[bias]\n" "v_mov_b32 v47, 0\n"
            "v_mov_b32 v50, %[bias]\n" "v_mov_b32 v51, 0\n"
            "v_mov_b32 v36, %[fa0]\n" "v_mov_b32 v37, %[fa1]\n"
            "v_mov_b32 v40, %[fb0]\n" "v_mov_b32 v41, %[fb1]\n"
            "v_mov_b32 v44, %[fc0]\n" "v_mov_b32 v45, %[fc1]\n"
            "v_mov_b32 v48, %[fd0]\n" "v_mov_b32 v49, %[fd1]\n"
            MFA("w0") MFB("w0") MFC("w0") MFD("w0")
            "s_nop 7\n" "s_nop 7\n" "s_nop 7\n"
            LAYER("w1")  LAYER("w2")  LAYER("w3")  LAYER("w4")
            LAYER("w5")  LAYER("w6")  LAYER("w7")  LAYER("w8")
            LAYER("w9")  LAYER("w10") LAYER("w11") LAYER("w12")
            LAYER("w13") LAYER("w14") LAYER("w15")
            "s_nop 7\n" "s_nop 7\n" "s_nop 7\n"
            "v_mov_b32 %[pA], v52\n"
            "v_mov_b32 %[pB], v56\n"
            "v_mov_b32 %[pC], v60\n"
            "v_mov_b32 %[pD], v64\n"
            : [pA] "=v"(pA), [pB] "=v"(pB), [pC] "=v"(pC), [pD] "=v"(pD)
            : [w0] "a"(wq[0]),  [w1] "a"(wq[1]),  [w2] "a"(wq[2]),
              [w3] "a"(wq[3]),  [w4] "a"(wq[4]),  [w5] "a"(wq[5]),
              [w6] "a"(wq[6]),  [w7] "a"(wq[7]),  [w8] "a"(wq[8]),
              [w9] "a"(wq[9]),  [w10] "a"(wq[10]), [w11] "a"(wq[11]),
              [w12] "a"(wq[12]), [w13] "a"(wq[13]), [w14] "a"(wq[14]),
              [w15] "a"(wq[15]),
              [fa0] "v"(fa0), [fa1] "v"(fa1), [fb0] "v"(fb0), [fb1] "v"(fb1),
              [fc0] "v"(fc0), [fc1] "v"(fc1), [fd0] "v"(fd0), [fd1] "v"(fd1),
              [bias] "v"(biasreg)
            : "v32","v33","v34","v35","v36","v37","v38","v39",
              "v40","v41","v42","v43","v44","v45","v46","v47",
              "v48","v49","v50","v51","v52","v53","v54","v55",
              "v56","v57","v58","v59","v60","v61","v62","v63",
              "v64","v65","v66","v67","v68","v69","v70","v71","v72");

        if (lane < 16) {                   // D row 0 = prediction, lanes 0..15
            const float qA = fminf(fmaxf(pA, -1.0f), 1.0f);
            const float uA = vA - qA + 1.0f;
            const float dA = uA - ((uA < 2.0f) ? 1.0f : 3.0f); // fmod(u,2)-1
            const float qB = fminf(fmaxf(pB, -1.0f), 1.0f);
            const float uB = vB - qB + 1.0f;
            const float dB = uB - ((uB < 2.0f) ? 1.0f : 3.0f);
            const float qC = fminf(fmaxf(pC, -1.0f), 1.0f);
            const float uC = vC - qC + 1.0f;
            const float dC = uC - ((uC < 2.0f) ? 1.0f : 3.0f);
            const float qD = fminf(fmaxf(pD, -1.0f), 1.0f);
            const float uD = vD - qD + 1.0f;
            const float dD = uD - ((uD < 2.0f) ? 1.0f : 3.0f);
            const int r = 2 * yi;
            stage[wv][r * 32 + t]            = dA;
            stage[wv][r * 32 + 16 + t]       = dB;
            stage[wv][(r + 1) * 32 + t]      = dC;
            stage[wv][(r + 1) * 32 + 16 + t] = dD;
            d2 = fmaf(dA, dA, fmaf(dB, dB, fmaf(dC, dC, fmaf(dD, dD, d2))));
        }
        e += 74;                            // two rows
    }

    // ---- coalesced delta store: wave's 256 floats = rows [8wv, 8wv+8) ----
    float* outp = out + 1 + (size_t)n * 1024 + wv * 256;
    #pragma unroll
    for (int j = 0; j < 4; ++j)
        outp[j * 64 + lane] = stage[wv][j * 64 + lane];

    // ---- loss reduction + fused finalize (relaxed atomics + pure waits) ----
    #pragma unroll
    for (int off = 8; off > 0; off >>= 1) d2 += __shfl_down(d2, off, 64);
    if (lane == 0) wsum[wv] = d2;
    __syncthreads();
    if (tid == 0) {
        const float s = wsum[0] + wsum[1] + wsum[2] + wsum[3];
        atomicAdd(loss_acc, s);             // relaxed, device-scope (m20)
        // order: my add ACK'd at coherence point before counter inc.
        asm volatile("s_waitcnt vmcnt(0)" ::: "memory");
        const unsigned old = atomicAdd(done_cnt, 1u);
        if (old == NBLK - 1) {
            const float tot = atomicAdd(loss_acc, 0.0f);  // atomic read
            out[0] = 255.0f * sqrtf(tot / (float)NPIX);
        }
    }
}

extern "C" void kernel_launch(void* const* d_in, const int* in_sizes, int n_in,
                              void* d_out, int out_size, void* d_ws, size_t ws_size,
                              hipStream_t stream)
{
    const float* x  = (const float*)d_in[0];
    const float* Wh = (const float*)d_in[1];
    const float* bh = (const float*)d_in[2];
    const float* Wo = (const float*)d_in[3];
    const float* bo = (const float*)d_in[4];
    float* out = (float*)d_out;
    float*    acc = (float*)d_ws;
    unsigned* cnt = (unsigned*)d_ws + 1;

    hipMemsetAsync(d_ws, 0, 8, stream);   // graph-capture safe
    codec_main<<<NBLK, 256, 0, stream>>>(x, Wh, bh, Wo, bo, out, acc, cnt);
}